// Round 2
// baseline (537.719 us; speedup 1.0000x reference)
//
#include <hip/hip_runtime.h>
#include <hip/hip_bf16.h>

typedef __bf16 bf16;
typedef __bf16 bf16x8 __attribute__((ext_vector_type(8)));
typedef __bf16 bf16x4 __attribute__((ext_vector_type(4)));
typedef float f32x4 __attribute__((ext_vector_type(4)));

#define NBIG 7168
#define KBIG 2048

__device__ __forceinline__ float sigmoid_f(float x) { return 1.0f / (1.0f + __expf(-x)); }
__device__ __forceinline__ float tanh_f(float x) { return 1.0f - 2.0f / (__expf(2.0f * x) + 1.0f); }

__device__ __forceinline__ void gload_lds16(const bf16* g, bf16* lds) {
  __builtin_amdgcn_global_load_lds(
      (const __attribute__((address_space(1))) unsigned int*)g,
      (__attribute__((address_space(3))) unsigned int*)lds,
      16, 0, 0);
}

// ---------------- prep kernels ----------------

__global__ __launch_bounds__(256) void build_A(const float* __restrict__ x,
                                               const float* __restrict__ h,
                                               bf16* __restrict__ A) {
  const int i4 = blockIdx.x * 256 + threadIdx.x;
  const int o = i4 * 4;
  const int m = o >> 11;
  const int c = o & 2047;
  const float4 v = (c < 1024) ? *(const float4*)&x[(size_t)m * 1024 + c]
                              : *(const float4*)&h[(size_t)m * 1024 + (c - 1024)];
  bf16x4 b;
  b[0] = (bf16)v.x; b[1] = (bf16)v.y; b[2] = (bf16)v.z; b[3] = (bf16)v.w;
  *(bf16x4*)&A[(size_t)o] = b;
}

__global__ __launch_bounds__(256) void build_WG(
    const float* __restrict__ Wi, const float* __restrict__ Wf, const float* __restrict__ Wo,
    const float* __restrict__ Wc, const float* __restrict__ Ws,
    const float* __restrict__ Ui, const float* __restrict__ Uf, const float* __restrict__ Uo,
    const float* __restrict__ Uc, const float* __restrict__ Us,
    const float* __restrict__ a1w, const float* __restrict__ r1w, bf16* __restrict__ WG) {
  const int i4 = blockIdx.x * 256 + threadIdx.x;
  const int o = i4 * 4;
  const int n = o >> 11;
  const int c = o & 2047;
  const int g = n >> 10;
  const int r = n & 1023;
  float4 v;
  if (g < 5) {
    const float* Wp = g == 0 ? Wi : g == 1 ? Wf : g == 2 ? Wo : g == 3 ? Wc : Ws;
    const float* Up = g == 0 ? Ui : g == 1 ? Uf : g == 2 ? Uo : g == 3 ? Uc : Us;
    v = (c < 1024) ? *(const float4*)&Wp[(size_t)r * 1024 + c]
                   : *(const float4*)&Up[(size_t)r * 1024 + (c - 1024)];
  } else if (g == 5) {
    v = *(const float4*)&a1w[(size_t)r * 2048 + c];
  } else {
    if (c < 1024) { v.x = 0.f; v.y = 0.f; v.z = 0.f; v.w = 0.f; }
    else v = *(const float4*)&r1w[(size_t)r * 1024 + (c - 1024)];
  }
  bf16x4 b;
  b[0] = (bf16)v.x; b[1] = (bf16)v.y; b[2] = (bf16)v.z; b[3] = (bf16)v.w;
  *(bf16x4*)&WG[(size_t)o] = b;
}

__global__ __launch_bounds__(256) void build_bias(
    const float* __restrict__ Wib, const float* __restrict__ Wfb, const float* __restrict__ Wob,
    const float* __restrict__ Wcb, const float* __restrict__ Wsb,
    const float* __restrict__ Uib, const float* __restrict__ Ufb, const float* __restrict__ Uob,
    const float* __restrict__ Ucb, const float* __restrict__ Usb,
    const float* __restrict__ a1b, const float* __restrict__ r1b, float* __restrict__ bias) {
  const int n = blockIdx.x * 256 + threadIdx.x;
  if (n >= NBIG) return;
  const int g = n >> 10, r = n & 1023;
  float v;
  if (g < 5) {
    const float* Wb = g == 0 ? Wib : g == 1 ? Wfb : g == 2 ? Wob : g == 3 ? Wcb : Wsb;
    const float* Ub = g == 0 ? Uib : g == 1 ? Ufb : g == 2 ? Uob : g == 3 ? Ucb : Usb;
    v = Wb[r] + Ub[r];
  } else if (g == 5) v = a1b[r];
  else v = r1b[r];
  bias[n] = v;
}

__global__ __launch_bounds__(256) void f2b(const float* __restrict__ s, bf16* __restrict__ d,
                                           int n4) {
  const int i = blockIdx.x * 256 + threadIdx.x;
  if (i >= n4) return;
  const float4 v = *(const float4*)&s[(size_t)i * 4];
  bf16x4 b;
  b[0] = (bf16)v.x; b[1] = (bf16)v.y; b[2] = (bf16)v.z; b[3] = (bf16)v.w;
  *(bf16x4*)&d[(size_t)i * 4] = b;
}

// ---------------- 256x256 8-phase GEMM: C = act(A @ W^T + bias) ----------------
// BM=BN=256, BK=64, 8 waves (2Mx4N), LDS 128 KiB double-buffered.
// Swizzle: LDS in-row byte ^= ((row&7)<<4); applied inversely on global stage source.
// act_mode 0: per-col regions (n>>10: 0,1,2,4=sigmoid, 3=tanh, 5,6=relu); 1: relu; 2: none.

#define BAR __builtin_amdgcn_s_barrier()
#define LGKM0 asm volatile("s_waitcnt lgkmcnt(0)" ::: "memory")
#define VM4 asm volatile("s_waitcnt vmcnt(4)" ::: "memory")
#define VM0 asm volatile("s_waitcnt vmcnt(0)" ::: "memory")
#define PRIO1 __builtin_amdgcn_s_setprio(1)
#define PRIO0 __builtin_amdgcn_s_setprio(0)

__global__ __launch_bounds__(512, 2) void gemm256(
    const bf16* __restrict__ A, int lda,
    const bf16* __restrict__ W, int ldw, int K,
    const float* __restrict__ bias,
    bf16* __restrict__ C, int ldc, int act_mode, int mtiles) {
  __shared__ __align__(16) bf16 sA[2][256 * 64];
  __shared__ __align__(16) bf16 sB[2][256 * 64];

  const int tid = threadIdx.x;
  const int lane = tid & 63;
  const int wv = tid >> 6;
  const int wr = wv >> 2;  // 0..1
  const int wc = wv & 3;   // 0..3

  // XCD-aware swizzle (nwg % 8 == 0 required for simple form)
  const int nwg = gridDim.x;
  int wg = blockIdx.x;
  if ((nwg & 7) == 0) wg = (wg & 7) * (nwg >> 3) + (wg >> 3);
  const int bm = (wg % mtiles) * 256;
  const int bn = (wg / mtiles) * 256;

  // staging constants: thread -> (row 0..63, slot 0..7); source col pre-swizzled
  const int srow = tid >> 3;
  const int scole = ((tid & 7) ^ (srow & 7)) << 3;
  const bf16* pA = A + (size_t)(bm + srow) * lda + scole;
  const bf16* pB = W + (size_t)(bn + srow) * ldw + scole;

  // frag-read constants (row&7 == lane&7 for all frag rows)
  const int fr = lane & 15;
  const int lg = lane >> 4;
  const int swz = (lane & 7) << 4;

  const int NT = K >> 6;

  f32x4 acc[8][4] = {};
  bf16x8 ar[4][2], br0[2][2], br1[2][2];

#define STG_A(bb, hh, tt)                                          \
  do {                                                             \
    const bf16* g_ = pA + (size_t)((hh) * 128) * lda + (tt) * 64;  \
    bf16* l_ = &sA[bb][((hh) * 128 + wv * 8) * 64];                \
    gload_lds16(g_, l_);                                           \
    gload_lds16(g_ + (size_t)64 * lda, l_ + 64 * 64);              \
  } while (0)
#define STG_B(bb, hh, tt)                                          \
  do {                                                             \
    const bf16* g_ = pB + (size_t)((hh) * 128) * ldw + (tt) * 64;  \
    bf16* l_ = &sB[bb][((hh) * 128 + wv * 8) * 64];                \
    gload_lds16(g_, l_);                                           \
    gload_lds16(g_ + (size_t)64 * ldw, l_ + 64 * 64);              \
  } while (0)
#define LD_A(bb, mlo)                                                            \
  do {                                                                           \
    _Pragma("unroll") for (int mi = 0; mi < 4; ++mi)                             \
    _Pragma("unroll") for (int kk = 0; kk < 2; ++kk)                             \
        ar[mi][kk] = *(const bf16x8*)((const char*)&sA[bb][0] +                  \
            (wr * 128 + ((mlo) + mi) * 16 + fr) * 128 +                          \
            ((lg * 16 + kk * 64) ^ swz));                                        \
  } while (0)
#define LD_B(dst, bb, nlo)                                                       \
  do {                                                                           \
    _Pragma("unroll") for (int ni = 0; ni < 2; ++ni)                             \
    _Pragma("unroll") for (int kk = 0; kk < 2; ++kk)                             \
        dst[ni][kk] = *(const bf16x8*)((const char*)&sB[bb][0] +                 \
            (wc * 64 + ((nlo) + ni) * 16 + fr) * 128 +                           \
            ((lg * 16 + kk * 64) ^ swz));                                        \
  } while (0)
#define MM(mlo, nlo, br)                                                         \
  do {                                                                           \
    _Pragma("unroll") for (int mi = 0; mi < 4; ++mi)                             \
    _Pragma("unroll") for (int ni = 0; ni < 2; ++ni) {                           \
      acc[(mlo) + mi][(nlo) + ni] = __builtin_amdgcn_mfma_f32_16x16x32_bf16(     \
          ar[mi][0], br[ni][0], acc[(mlo) + mi][(nlo) + ni], 0, 0, 0);           \
      acc[(mlo) + mi][(nlo) + ni] = __builtin_amdgcn_mfma_f32_16x16x32_bf16(     \
          ar[mi][1], br[ni][1], acc[(mlo) + mi][(nlo) + ni], 0, 0, 0);           \
    }                                                                            \
  } while (0)

  // prologue: tile0 (all 4 halves) -> buf0; tile1 B halves -> buf1
  STG_A(0, 0, 0); STG_A(0, 1, 0); STG_B(0, 0, 0); STG_B(0, 1, 0);
  STG_B(1, 0, 1); STG_B(1, 1, 1);
  VM4; BAR;

  for (int t = 0; t + 3 < NT; t += 2) {
    // P1: tile t (buf0), quadrant (Mlo,Nlo)
    LD_A(0, 0); LD_B(br0, 0, 0); STG_A(1, 0, t + 1);
    BAR; LGKM0; PRIO1; MM(0, 0, br0); PRIO0; BAR;
    // P2: (Mlo,Nhi)
    LD_B(br1, 0, 2); STG_A(1, 1, t + 1);
    BAR; LGKM0; PRIO1; MM(0, 2, br1); PRIO0; BAR;
    // P3: (Mhi,Nhi)
    LD_A(0, 4); STG_B(0, 0, t + 2);
    BAR; LGKM0; PRIO1; MM(4, 2, br1); PRIO0; BAR;
    // P4: (Mhi,Nlo); counted vmcnt — A(t+1) complete, B(t+2) in flight
    STG_B(0, 1, t + 2);
    BAR; PRIO1; MM(4, 0, br0); PRIO0; VM4; BAR;
    // P5: tile t+1 (buf1)
    LD_A(1, 0); LD_B(br0, 1, 0); STG_A(0, 0, t + 2);
    BAR; LGKM0; PRIO1; MM(0, 0, br0); PRIO0; BAR;
    // P6
    LD_B(br1, 1, 2); STG_A(0, 1, t + 2);
    BAR; LGKM0; PRIO1; MM(0, 2, br1); PRIO0; BAR;
    // P7
    LD_A(1, 4); STG_B(1, 0, t + 3);
    BAR; LGKM0; PRIO1; MM(4, 2, br1); PRIO0; BAR;
    // P8
    STG_B(1, 1, t + 3);
    BAR; PRIO1; MM(4, 0, br0); PRIO0; VM4; BAR;
  }

  // epilogue: tiles NT-2 (buf0), NT-1 (buf1)
  LD_A(0, 0); LD_B(br0, 0, 0); STG_A(1, 0, NT - 1);
  BAR; LGKM0; PRIO1; MM(0, 0, br0); PRIO0; BAR;
  LD_B(br1, 0, 2); STG_A(1, 1, NT - 1);
  BAR; LGKM0; PRIO1; MM(0, 2, br1); PRIO0; BAR;
  LD_A(0, 4);
  BAR; LGKM0; PRIO1; MM(4, 2, br1); PRIO0; BAR;
  PRIO1; MM(4, 0, br0); PRIO0; VM0; BAR;
  LD_A(1, 0); LD_B(br0, 1, 0);
  BAR; LGKM0; PRIO1; MM(0, 0, br0); PRIO0; BAR;
  LD_B(br1, 1, 2);
  BAR; LGKM0; PRIO1; MM(0, 2, br1); PRIO0; BAR;
  LD_A(1, 4);
  BAR; LGKM0; PRIO1; MM(4, 2, br1); PRIO0; BAR;
  PRIO1; MM(4, 0, br0); PRIO0;

  // C-write: C/D layout col = lane&15, row = (lane>>4)*4 + r
  const int rbase = lg * 4;
#pragma unroll
  for (int j = 0; j < 4; ++j) {
    const int n = bn + wc * 64 + j * 16 + fr;
    const float bv = bias[n];
    const int g = (act_mode == 0) ? (n >> 10) : (act_mode == 1 ? 100 : 101);
#pragma unroll
    for (int mi = 0; mi < 8; ++mi) {
      const size_t mrow = (size_t)(bm + wr * 128 + mi * 16 + rbase);
#pragma unroll
      for (int r = 0; r < 4; ++r) {
        float v = acc[mi][j][r] + bv;
        if (g == 3) v = tanh_f(v);
        else if (g < 5) v = sigmoid_f(v);
        else if (g < 7 || g == 100) v = fmaxf(v, 0.0f);
        C[(mrow + r) * (size_t)ldc + n] = (bf16)v;
      }
    }
  }
#undef STG_A
#undef STG_B
#undef LD_A
#undef LD_B
#undef MM
}

// ---------------- 128x128 GEMM (kept for residual chain) ----------------
__global__ __launch_bounds__(256) void gemm_bt(const bf16* __restrict__ A, int lda,
                                               const bf16* __restrict__ W, int K,
                                               const float* __restrict__ bias,
                                               bf16* __restrict__ C, int ldc, int act_mode) {
  __shared__ __align__(16) bf16 As[128 * 32];
  __shared__ __align__(16) bf16 Bs[128 * 32];

  const int tid = threadIdx.x;
  const int lane = tid & 63;
  const int wv = tid >> 6;
  const int bm = blockIdx.x * 128;
  const int bn = blockIdx.y * 128;
  const int wr = wv >> 1, wc = wv & 1;

  const int srow = wv * 16 + (lane >> 2);
  const int scol = (lane & 3) * 8;
  const bf16* ag0 = A + (size_t)(bm + srow) * lda + scol;
  const bf16* ag1 = ag0 + (size_t)64 * lda;
  const bf16* bg0 = W + (size_t)(bn + srow) * K + scol;
  const bf16* bg1 = bg0 + (size_t)64 * K;
  bf16* const al0 = &As[(wv * 16) * 32];
  bf16* const al1 = &As[(64 + wv * 16) * 32];
  bf16* const bl0 = &Bs[(wv * 16) * 32];
  bf16* const bl1 = &Bs[(64 + wv * 16) * 32];

  f32x4 acc[4][4] = {};

  const int k0 = (lane >> 4) * 8;
  const int fr = lane & 15;
  const int niter = K >> 5;
  for (int kt = 0; kt < niter; ++kt) {
    __syncthreads();
    gload_lds16(ag0, al0);
    gload_lds16(ag1, al1);
    gload_lds16(bg0, bl0);
    gload_lds16(bg1, bl1);
    ag0 += 32; ag1 += 32; bg0 += 32; bg1 += 32;
    __syncthreads();

    bf16x8 af[4], bfv[4];
#pragma unroll
    for (int f = 0; f < 4; ++f) {
      af[f] = *(const bf16x8*)&As[(wr * 64 + f * 16 + fr) * 32 + k0];
      bfv[f] = *(const bf16x8*)&Bs[(wc * 64 + f * 16 + fr) * 32 + k0];
    }
#pragma unroll
    for (int i = 0; i < 4; ++i)
#pragma unroll
      for (int j = 0; j < 4; ++j)
        acc[i][j] = __builtin_amdgcn_mfma_f32_16x16x32_bf16(af[i], bfv[j], acc[i][j], 0, 0, 0);
  }

  const int rbase = (lane >> 4) * 4;
#pragma unroll
  for (int j = 0; j < 4; ++j) {
    const int n = bn + wc * 64 + j * 16 + fr;
    const float bv = bias[n];
    const int g = (act_mode == 0) ? (n >> 10) : (act_mode == 1 ? 100 : 101);
#pragma unroll
    for (int i = 0; i < 4; ++i) {
      const size_t mrow = (size_t)(bm + wr * 64 + i * 16 + rbase);
#pragma unroll
      for (int r = 0; r < 4; ++r) {
        float v = acc[i][j][r] + bv;
        if (g == 3) v = tanh_f(v);
        else if (g < 5) v = sigmoid_f(v);
        else if (g < 7 || g == 100) v = fmaxf(v, 0.0f);
        C[(mrow + r) * (size_t)ldc + n] = (bf16)v;
      }
    }
  }
}

// ---------------- alpha head ----------------
__global__ __launch_bounds__(256) void alpha_k(const bf16* __restrict__ G,
                                               const float* __restrict__ a2w,
                                               const float* __restrict__ a2b,
                                               float* __restrict__ alpha) {
  const int m = blockIdx.x * 4 + (threadIdx.x >> 6);
  const int lane = threadIdx.x & 63;
  const bf16* row = G + (size_t)m * NBIG + 5120 + lane * 16;
  const bf16x8 v0 = *(const bf16x8*)row;
  const bf16x8 v1 = *(const bf16x8*)(row + 8);
  const float* w = a2w + lane * 16;
  float s = 0.f;
#pragma unroll
  for (int e = 0; e < 8; ++e) s += (float)v0[e] * w[e] + (float)v1[e] * w[8 + e];
#pragma unroll
  for (int off = 32; off > 0; off >>= 1) s += __shfl_down(s, off, 64);
  if (lane == 0) alpha[m] = sigmoid_f(s + a2b[0]);
}

// ---------------- final elementwise ----------------
__global__ __launch_bounds__(256) void final_k(const bf16* __restrict__ G,
                                               const bf16* __restrict__ R3,
                                               const float* __restrict__ c_prev,
                                               const float* __restrict__ alpha,
                                               float* __restrict__ out) {
  const int idx = blockIdx.x * 256 + threadIdx.x;
  const int o = idx * 8;
  const int m = o >> 10;
  const int c = o & 1023;
  const size_t gb = (size_t)m * NBIG;
  const bf16x8 iv = *(const bf16x8*)&G[gb + c];
  const bf16x8 fv = *(const bf16x8*)&G[gb + 1024 + c];
  const bf16x8 ov = *(const bf16x8*)&G[gb + 2048 + c];
  const bf16x8 cv = *(const bf16x8*)&G[gb + 3072 + c];
  const bf16x8 sv = *(const bf16x8*)&G[gb + 4096 + c];
  const bf16x8 rv = *(const bf16x8*)&R3[(size_t)m * 1024 + c];
  const float al = alpha[m];
  const float* cp = &c_prev[(size_t)m * 1024 + c];
  float hbuf[8], cbuf[8];
#pragma unroll
  for (int e = 0; e < 8; ++e) {
    const float ct = (float)fv[e] * cp[e] + (float)iv[e] * (float)cv[e] * (float)sv[e] * al
                     + (float)rv[e];
    cbuf[e] = ct;
    hbuf[e] = (float)ov[e] * tanh_f(ct);
  }
  float* oh = out + (size_t)m * 1024 + c;
  float* oc = out + (size_t)8192 * 1024 + (size_t)m * 1024 + c;
#pragma unroll
  for (int e = 0; e < 8; ++e) { oh[e] = hbuf[e]; oc[e] = cbuf[e]; }
}

// ---------------- launch ----------------
extern "C" void kernel_launch(void* const* d_in, const int* in_sizes, int n_in,
                              void* d_out, int out_size, void* d_ws, size_t ws_size,
                              hipStream_t stream) {
  const float* x      = (const float*)d_in[0];
  const float* h_prev = (const float*)d_in[1];
  const float* c_prev = (const float*)d_in[2];
  const float* Wi_w = (const float*)d_in[3];  const float* Wi_b = (const float*)d_in[4];
  const float* Wf_w = (const float*)d_in[5];  const float* Wf_b = (const float*)d_in[6];
  const float* Wo_w = (const float*)d_in[7];  const float* Wo_b = (const float*)d_in[8];
  const float* Wc_w = (const float*)d_in[9];  const float* Wc_b = (const float*)d_in[10];
  const float* Ws_w = (const float*)d_in[11]; const float* Ws_b = (const float*)d_in[12];
  const float* Ui_w = (const float*)d_in[13]; const float* Ui_b = (const float*)d_in[14];
  const float* Uf_w = (const float*)d_in[15]; const float* Uf_b = (const float*)d_in[16];
  const float* Uo_w = (const float*)d_in[17]; const float* Uo_b = (const float*)d_in[18];
  const float* Uc_w = (const float*)d_in[19]; const float* Uc_b = (const float*)d_in[20];
  const float* Us_w = (const float*)d_in[21]; const float* Us_b = (const float*)d_in[22];
  const float* a1_w = (const float*)d_in[23]; const float* a1_b = (const float*)d_in[24];
  const float* a2_w = (const float*)d_in[25]; const float* a2_b = (const float*)d_in[26];
  const float* r1_w = (const float*)d_in[27]; const float* r1_b = (const float*)d_in[28];
  const float* r2_w = (const float*)d_in[29]; const float* r2_b = (const float*)d_in[30];
  const float* r3_w = (const float*)d_in[31]; const float* r3_b = (const float*)d_in[32];

  char* ws = (char*)d_ws;
  size_t off = 0;
  auto alloc = [&](size_t bytes) -> void* {
    void* p = ws + off;
    off += (bytes + 255) & ~(size_t)255;
    return p;
  };
  bf16* A_big    = (bf16*)alloc((size_t)8192 * 2048 * 2);
  bf16* WG       = (bf16*)alloc((size_t)7168 * 2048 * 2);
  float* bias_bg = (float*)alloc((size_t)7168 * 4);
  bf16* WR2      = (bf16*)alloc((size_t)1024 * 1024 * 2);
  bf16* WR3      = (bf16*)alloc((size_t)1024 * 1024 * 2);
  bf16* G        = (bf16*)alloc((size_t)8192 * 7168 * 2);
  bf16* R2       = (bf16*)alloc((size_t)8192 * 1024 * 2);
  bf16* R3       = (bf16*)alloc((size_t)8192 * 1024 * 2);
  float* alpha   = (float*)alloc((size_t)8192 * 4);

  build_A<<<16384, 256, 0, stream>>>(x, h_prev, A_big);
  build_WG<<<14336, 256, 0, stream>>>(Wi_w, Wf_w, Wo_w, Wc_w, Ws_w,
                                      Ui_w, Uf_w, Uo_w, Uc_w, Us_w, a1_w, r1_w, WG);
  build_bias<<<28, 256, 0, stream>>>(Wi_b, Wf_b, Wo_b, Wc_b, Ws_b,
                                     Ui_b, Uf_b, Uo_b, Uc_b, Us_b, a1_b, r1_b, bias_bg);
  f2b<<<1024, 256, 0, stream>>>(r2_w, WR2, 262144);
  f2b<<<1024, 256, 0, stream>>>(r3_w, WR3, 262144);

  // big fused GEMM: [8192 x 2048] @ [7168 x 2048]^T, 256^2 8-phase
  gemm256<<<32 * 28, 512, 0, stream>>>(A_big, 2048, WG, 2048, 2048, bias_bg, G, NBIG, 0, 32);

  // alpha head
  alpha_k<<<2048, 256, 0, stream>>>(G, a2_w, a2_b, alpha);

  // residual chain r2 -> r3 (128^2 kernel)
  dim3 g2(64, 8);
  gemm_bt<<<g2, 256, 0, stream>>>(G + 6144, NBIG, WR2, 1024, r2_b, R2, 1024, 1);
  gemm_bt<<<g2, 256, 0, stream>>>(R2, 1024, WR3, 1024, r3_b, R3, 1024, 2);

  final_k<<<4096, 256, 0, stream>>>(G, R3, c_prev, alpha, (float*)d_out);
}

// Round 3
// 503.547 us; speedup vs baseline: 1.0679x; 1.0679x over previous
//
#include <hip/hip_runtime.h>
#include <hip/hip_bf16.h>

typedef __bf16 bf16;
typedef __bf16 bf16x8 __attribute__((ext_vector_type(8)));
typedef __bf16 bf16x4 __attribute__((ext_vector_type(4)));
typedef float f32x4 __attribute__((ext_vector_type(4)));

#define NBIG 7168
#define KBIG 2048

__device__ __forceinline__ float sigmoid_f(float x) { return 1.0f / (1.0f + __expf(-x)); }
__device__ __forceinline__ float tanh_f(float x) { return 1.0f - 2.0f / (__expf(2.0f * x) + 1.0f); }

__device__ __forceinline__ void gload_lds16(const bf16* g, bf16* lds) {
  __builtin_amdgcn_global_load_lds(
      (const __attribute__((address_space(1))) unsigned int*)g,
      (__attribute__((address_space(3))) unsigned int*)lds,
      16, 0, 0);
}

// ---------------- prep kernels ----------------

__global__ __launch_bounds__(256) void build_A(const float* __restrict__ x,
                                               const float* __restrict__ h,
                                               bf16* __restrict__ A) {
  const int i4 = blockIdx.x * 256 + threadIdx.x;
  const int o = i4 * 4;
  const int m = o >> 11;
  const int c = o & 2047;
  const float4 v = (c < 1024) ? *(const float4*)&x[(size_t)m * 1024 + c]
                              : *(const float4*)&h[(size_t)m * 1024 + (c - 1024)];
  bf16x4 b;
  b[0] = (bf16)v.x; b[1] = (bf16)v.y; b[2] = (bf16)v.z; b[3] = (bf16)v.w;
  *(bf16x4*)&A[(size_t)o] = b;
}

__global__ __launch_bounds__(256) void build_WG(
    const float* __restrict__ Wi, const float* __restrict__ Wf, const float* __restrict__ Wo,
    const float* __restrict__ Wc, const float* __restrict__ Ws,
    const float* __restrict__ Ui, const float* __restrict__ Uf, const float* __restrict__ Uo,
    const float* __restrict__ Uc, const float* __restrict__ Us,
    const float* __restrict__ a1w, const float* __restrict__ r1w, bf16* __restrict__ WG) {
  const int i4 = blockIdx.x * 256 + threadIdx.x;
  const int o = i4 * 4;
  const int n = o >> 11;
  const int c = o & 2047;
  const int g = n >> 10;
  const int r = n & 1023;
  float4 v;
  if (g < 5) {
    const float* Wp = g == 0 ? Wi : g == 1 ? Wf : g == 2 ? Wo : g == 3 ? Wc : Ws;
    const float* Up = g == 0 ? Ui : g == 1 ? Uf : g == 2 ? Uo : g == 3 ? Uc : Us;
    v = (c < 1024) ? *(const float4*)&Wp[(size_t)r * 1024 + c]
                   : *(const float4*)&Up[(size_t)r * 1024 + (c - 1024)];
  } else if (g == 5) {
    v = *(const float4*)&a1w[(size_t)r * 2048 + c];
  } else {
    if (c < 1024) { v.x = 0.f; v.y = 0.f; v.z = 0.f; v.w = 0.f; }
    else v = *(const float4*)&r1w[(size_t)r * 1024 + (c - 1024)];
  }
  bf16x4 b;
  b[0] = (bf16)v.x; b[1] = (bf16)v.y; b[2] = (bf16)v.z; b[3] = (bf16)v.w;
  *(bf16x4*)&WG[(size_t)o] = b;
}

__global__ __launch_bounds__(256) void build_bias(
    const float* __restrict__ Wib, const float* __restrict__ Wfb, const float* __restrict__ Wob,
    const float* __restrict__ Wcb, const float* __restrict__ Wsb,
    const float* __restrict__ Uib, const float* __restrict__ Ufb, const float* __restrict__ Uob,
    const float* __restrict__ Ucb, const float* __restrict__ Usb,
    const float* __restrict__ a1b, const float* __restrict__ r1b, float* __restrict__ bias) {
  const int n = blockIdx.x * 256 + threadIdx.x;
  if (n >= NBIG) return;
  const int g = n >> 10, r = n & 1023;
  float v;
  if (g < 5) {
    const float* Wb = g == 0 ? Wib : g == 1 ? Wfb : g == 2 ? Wob : g == 3 ? Wcb : Wsb;
    const float* Ub = g == 0 ? Uib : g == 1 ? Ufb : g == 2 ? Uob : g == 3 ? Ucb : Usb;
    v = Wb[r] + Ub[r];
  } else if (g == 5) v = a1b[r];
  else v = r1b[r];
  bias[n] = v;
}

__global__ __launch_bounds__(256) void f2b(const float* __restrict__ s, bf16* __restrict__ d,
                                           int n4) {
  const int i = blockIdx.x * 256 + threadIdx.x;
  if (i >= n4) return;
  const float4 v = *(const float4*)&s[(size_t)i * 4];
  bf16x4 b;
  b[0] = (bf16)v.x; b[1] = (bf16)v.y; b[2] = (bf16)v.z; b[3] = (bf16)v.w;
  *(bf16x4*)&d[(size_t)i * 4] = b;
}

// ---------------- 256x256 8-phase GEMM: C = act(A @ W^T + bias) ----------------
// BM=BN=256, BK=64, 8 waves (2Mx4N), LDS 128 KiB double-buffered.
// Tile-granular deep prefetch: full tile t+2 staged at P4 (VM8), t+3 at P8.
// Swizzle: LDS in-row byte ^= ((row&7)<<4); applied inversely on global stage source.
// act_mode 0: per-col regions (n>>10: 0,1,2,4=sigmoid, 3=tanh, 5,6=relu); 1: relu; 2: none.

#define BAR __builtin_amdgcn_s_barrier()
#define LGKM0 asm volatile("s_waitcnt lgkmcnt(0)" ::: "memory")
#define VM8 asm volatile("s_waitcnt vmcnt(8)" ::: "memory")
#define VM0 asm volatile("s_waitcnt vmcnt(0)" ::: "memory")
#define PRIO1 __builtin_amdgcn_s_setprio(1)
#define PRIO0 __builtin_amdgcn_s_setprio(0)

__global__ __launch_bounds__(512, 2) void gemm256(
    const bf16* __restrict__ A, int lda,
    const bf16* __restrict__ W, int ldw, int K,
    const float* __restrict__ bias,
    bf16* __restrict__ C, int ldc, int act_mode, int mtiles) {
  __shared__ __align__(16) bf16 sA[2][256 * 64];
  __shared__ __align__(16) bf16 sB[2][256 * 64];

  const int tid = threadIdx.x;
  const int lane = tid & 63;
  const int wv = tid >> 6;
  const int wr = wv >> 2;  // 0..1
  const int wc = wv & 3;   // 0..3

  // Block mapping. 896 blocks: 8 XCD rectangles (2x4) of 16bm x 7bn, bn-fastest
  // inside each rectangle -> concurrent blocks on one XCD share few A/B panels.
  int bmi, bni;
  if (gridDim.x == 896) {
    const int xcd = blockIdx.x & 7;   // dispatch round-robins XCDs
    const int idx = blockIdx.x >> 3;  // 0..111 within XCD
    bmi = (xcd >> 2) * 16 + idx / 7;
    bni = (xcd & 3) * 7 + idx % 7;
  } else {
    bmi = blockIdx.x % mtiles;
    bni = blockIdx.x / mtiles;
  }
  const int bm = bmi * 256;
  const int bn = bni * 256;

  // staging constants: thread -> (row 0..63, slot 0..7); source col pre-swizzled
  const int srow = tid >> 3;
  const int scole = ((tid & 7) ^ (srow & 7)) << 3;
  const bf16* pA = A + (size_t)(bm + srow) * lda + scole;
  const bf16* pB = W + (size_t)(bn + srow) * ldw + scole;

  // frag-read constants
  const int fr = lane & 15;
  const int lg = lane >> 4;
  const int swz = (lane & 7) << 4;

  const int NT = K >> 6;

  f32x4 acc[8][4] = {};
  bf16x8 ar[4][2], br0[2][2], br1[2][2];

#define STG_A(bb, hh, tt)                                          \
  do {                                                             \
    const bf16* g_ = pA + (size_t)((hh) * 128) * lda + (tt) * 64;  \
    bf16* l_ = &sA[bb][((hh) * 128 + wv * 8) * 64];                \
    gload_lds16(g_, l_);                                           \
    gload_lds16(g_ + (size_t)64 * lda, l_ + 64 * 64);              \
  } while (0)
#define STG_B(bb, hh, tt)                                          \
  do {                                                             \
    const bf16* g_ = pB + (size_t)((hh) * 128) * ldw + (tt) * 64;  \
    bf16* l_ = &sB[bb][((hh) * 128 + wv * 8) * 64];                \
    gload_lds16(g_, l_);                                           \
    gload_lds16(g_ + (size_t)64 * ldw, l_ + 64 * 64);              \
  } while (0)
#define STGT(bb, tt)                                               \
  do {                                                             \
    STG_A(bb, 0, tt); STG_A(bb, 1, tt);                            \
    STG_B(bb, 0, tt); STG_B(bb, 1, tt);                            \
  } while (0)
#define LD_A(bb, mlo)                                                            \
  do {                                                                           \
    _Pragma("unroll") for (int mi = 0; mi < 4; ++mi)                             \
    _Pragma("unroll") for (int kk = 0; kk < 2; ++kk)                             \
        ar[mi][kk] = *(const bf16x8*)((const char*)&sA[bb][0] +                  \
            (wr * 128 + ((mlo) + mi) * 16 + fr) * 128 +                          \
            ((lg * 16 + kk * 64) ^ swz));                                        \
  } while (0)
#define LD_B(dst, bb, nlo)                                                       \
  do {                                                                           \
    _Pragma("unroll") for (int ni = 0; ni < 2; ++ni)                             \
    _Pragma("unroll") for (int kk = 0; kk < 2; ++kk)                             \
        dst[ni][kk] = *(const bf16x8*)((const char*)&sB[bb][0] +                 \
            (wc * 64 + ((nlo) + ni) * 16 + fr) * 128 +                           \
            ((lg * 16 + kk * 64) ^ swz));                                        \
  } while (0)
#define MM(mlo, nlo, br)                                                         \
  do {                                                                           \
    _Pragma("unroll") for (int mi = 0; mi < 4; ++mi)                             \
    _Pragma("unroll") for (int ni = 0; ni < 2; ++ni) {                           \
      acc[(mlo) + mi][(nlo) + ni] = __builtin_amdgcn_mfma_f32_16x16x32_bf16(     \
          ar[mi][0], br[ni][0], acc[(mlo) + mi][(nlo) + ni], 0, 0, 0);           \
      acc[(mlo) + mi][(nlo) + ni] = __builtin_amdgcn_mfma_f32_16x16x32_bf16(     \
          ar[mi][1], br[ni][1], acc[(mlo) + mi][(nlo) + ni], 0, 0, 0);           \
    }                                                                            \
  } while (0)

  // prologue: tile0 -> buf0, tile1 -> buf1. VM8 completes tile0; tile1 (8) in flight.
  STGT(0, 0);
  STGT(1, 1);
  VM8; BAR;

  for (int t = 0; t + 3 < NT; t += 2) {
    // ---- tile t (buf0) ----
    LD_A(0, 0); LD_B(br0, 0, 0);
    BAR; LGKM0; PRIO1; MM(0, 0, br0); PRIO0; BAR;
    LD_B(br1, 0, 2);
    BAR; LGKM0; PRIO1; MM(0, 2, br1); PRIO0; BAR;
    LD_A(0, 4);
    BAR; LGKM0; PRIO1; MM(4, 2, br1); PRIO0; BAR;
    STGT(0, t + 2);  // buf0 free (A last read P3, B last read P2)
    BAR; PRIO1; MM(4, 0, br0); PRIO0; VM8; BAR;  // completes tile t+1
    // ---- tile t+1 (buf1) ----
    LD_A(1, 0); LD_B(br0, 1, 0);
    BAR; LGKM0; PRIO1; MM(0, 0, br0); PRIO0; BAR;
    LD_B(br1, 1, 2);
    BAR; LGKM0; PRIO1; MM(0, 2, br1); PRIO0; BAR;
    LD_A(1, 4);
    BAR; LGKM0; PRIO1; MM(4, 2, br1); PRIO0; BAR;
    STGT(1, t + 3);
    BAR; PRIO1; MM(4, 0, br0); PRIO0; VM8; BAR;  // completes tile t+2
  }

  // epilogue: tiles NT-2 (buf0, complete), NT-1 (buf1, 8 loads in flight)
  LD_A(0, 0); LD_B(br0, 0, 0);
  BAR; LGKM0; PRIO1; MM(0, 0, br0); PRIO0; BAR;
  LD_B(br1, 0, 2);
  BAR; LGKM0; PRIO1; MM(0, 2, br1); PRIO0; BAR;
  LD_A(0, 4);
  BAR; LGKM0; PRIO1; MM(4, 2, br1); PRIO0; BAR;
  PRIO1; MM(4, 0, br0); PRIO0; VM0; BAR;  // drain tile NT-1
  LD_A(1, 0); LD_B(br0, 1, 0);
  BAR; LGKM0; PRIO1; MM(0, 0, br0); PRIO0; BAR;
  LD_B(br1, 1, 2);
  BAR; LGKM0; PRIO1; MM(0, 2, br1); PRIO0; BAR;
  LD_A(1, 4);
  BAR; LGKM0; PRIO1; MM(4, 2, br1); PRIO0; BAR;
  PRIO1; MM(4, 0, br0); PRIO0;

  // C-write: C/D layout col = lane&15, row = (lane>>4)*4 + r
  const int rbase = lg * 4;
#pragma unroll
  for (int j = 0; j < 4; ++j) {
    const int n = bn + wc * 64 + j * 16 + fr;
    const float bv = bias[n];
    const int g = (act_mode == 0) ? (n >> 10) : (act_mode == 1 ? 100 : 101);
#pragma unroll
    for (int mi = 0; mi < 8; ++mi) {
      const size_t mrow = (size_t)(bm + wr * 128 + mi * 16 + rbase);
#pragma unroll
      for (int r = 0; r < 4; ++r) {
        float v = acc[mi][j][r] + bv;
        if (g == 3) v = tanh_f(v);
        else if (g < 5) v = sigmoid_f(v);
        else if (g < 7 || g == 100) v = fmaxf(v, 0.0f);
        C[(mrow + r) * (size_t)ldc + n] = (bf16)v;
      }
    }
  }
#undef STG_A
#undef STG_B
#undef STGT
#undef LD_A
#undef LD_B
#undef MM
}

// ---------------- 128x128 GEMM (kept for residual chain) ----------------
__global__ __launch_bounds__(256) void gemm_bt(const bf16* __restrict__ A, int lda,
                                               const bf16* __restrict__ W, int K,
                                               const float* __restrict__ bias,
                                               bf16* __restrict__ C, int ldc, int act_mode) {
  __shared__ __align__(16) bf16 As[128 * 32];
  __shared__ __align__(16) bf16 Bs[128 * 32];

  const int tid = threadIdx.x;
  const int lane = tid & 63;
  const int wv = tid >> 6;
  const int bm = blockIdx.x * 128;
  const int bn = blockIdx.y * 128;
  const int wr = wv >> 1, wc = wv & 1;

  const int srow = wv * 16 + (lane >> 2);
  const int scol = (lane & 3) * 8;
  const bf16* ag0 = A + (size_t)(bm + srow) * lda + scol;
  const bf16* ag1 = ag0 + (size_t)64 * lda;
  const bf16* bg0 = W + (size_t)(bn + srow) * K + scol;
  const bf16* bg1 = bg0 + (size_t)64 * K;
  bf16* const al0 = &As[(wv * 16) * 32];
  bf16* const al1 = &As[(64 + wv * 16) * 32];
  bf16* const bl0 = &Bs[(wv * 16) * 32];
  bf16* const bl1 = &Bs[(64 + wv * 16) * 32];

  f32x4 acc[4][4] = {};

  const int k0 = (lane >> 4) * 8;
  const int fr = lane & 15;
  const int niter = K >> 5;
  for (int kt = 0; kt < niter; ++kt) {
    __syncthreads();
    gload_lds16(ag0, al0);
    gload_lds16(ag1, al1);
    gload_lds16(bg0, bl0);
    gload_lds16(bg1, bl1);
    ag0 += 32; ag1 += 32; bg0 += 32; bg1 += 32;
    __syncthreads();

    bf16x8 af[4], bfv[4];
#pragma unroll
    for (int f = 0; f < 4; ++f) {
      af[f] = *(const bf16x8*)&As[(wr * 64 + f * 16 + fr) * 32 + k0];
      bfv[f] = *(const bf16x8*)&Bs[(wc * 64 + f * 16 + fr) * 32 + k0];
    }
#pragma unroll
    for (int i = 0; i < 4; ++i)
#pragma unroll
      for (int j = 0; j < 4; ++j)
        acc[i][j] = __builtin_amdgcn_mfma_f32_16x16x32_bf16(af[i], bfv[j], acc[i][j], 0, 0, 0);
  }

  const int rbase = (lane >> 4) * 4;
#pragma unroll
  for (int j = 0; j < 4; ++j) {
    const int n = bn + wc * 64 + j * 16 + fr;
    const float bv = bias[n];
    const int g = (act_mode == 0) ? (n >> 10) : (act_mode == 1 ? 100 : 101);
#pragma unroll
    for (int i = 0; i < 4; ++i) {
      const size_t mrow = (size_t)(bm + wr * 64 + i * 16 + rbase);
#pragma unroll
      for (int r = 0; r < 4; ++r) {
        float v = acc[i][j][r] + bv;
        if (g == 3) v = tanh_f(v);
        else if (g < 5) v = sigmoid_f(v);
        else if (g < 7 || g == 100) v = fmaxf(v, 0.0f);
        C[(mrow + r) * (size_t)ldc + n] = (bf16)v;
      }
    }
  }
}

// ---------------- alpha head ----------------
__global__ __launch_bounds__(256) void alpha_k(const bf16* __restrict__ G,
                                               const float* __restrict__ a2w,
                                               const float* __restrict__ a2b,
                                               float* __restrict__ alpha) {
  const int m = blockIdx.x * 4 + (threadIdx.x >> 6);
  const int lane = threadIdx.x & 63;
  const bf16* row = G + (size_t)m * NBIG + 5120 + lane * 16;
  const bf16x8 v0 = *(const bf16x8*)row;
  const bf16x8 v1 = *(const bf16x8*)(row + 8);
  const float* w = a2w + lane * 16;
  float s = 0.f;
#pragma unroll
  for (int e = 0; e < 8; ++e) s += (float)v0[e] * w[e] + (float)v1[e] * w[8 + e];
#pragma unroll
  for (int off = 32; off > 0; off >>= 1) s += __shfl_down(s, off, 64);
  if (lane == 0) alpha[m] = sigmoid_f(s + a2b[0]);
}

// ---------------- final elementwise ----------------
__global__ __launch_bounds__(256) void final_k(const bf16* __restrict__ G,
                                               const bf16* __restrict__ R3,
                                               const float* __restrict__ c_prev,
                                               const float* __restrict__ alpha,
                                               float* __restrict__ out) {
  const int idx = blockIdx.x * 256 + threadIdx.x;
  const int o = idx * 8;
  const int m = o >> 10;
  const int c = o & 1023;
  const size_t gb = (size_t)m * NBIG;
  const bf16x8 iv = *(const bf16x8*)&G[gb + c];
  const bf16x8 fv = *(const bf16x8*)&G[gb + 1024 + c];
  const bf16x8 ov = *(const bf16x8*)&G[gb + 2048 + c];
  const bf16x8 cv = *(const bf16x8*)&G[gb + 3072 + c];
  const bf16x8 sv = *(const bf16x8*)&G[gb + 4096 + c];
  const bf16x8 rv = *(const bf16x8*)&R3[(size_t)m * 1024 + c];
  const float al = alpha[m];
  const float* cp = &c_prev[(size_t)m * 1024 + c];
  float hbuf[8], cbuf[8];
#pragma unroll
  for (int e = 0; e < 8; ++e) {
    const float ct = (float)fv[e] * cp[e] + (float)iv[e] * (float)cv[e] * (float)sv[e] * al
                     + (float)rv[e];
    cbuf[e] = ct;
    hbuf[e] = (float)ov[e] * tanh_f(ct);
  }
  float* oh = out + (size_t)m * 1024 + c;
  float* oc = out + (size_t)8192 * 1024 + (size_t)m * 1024 + c;
#pragma unroll
  for (int e = 0; e < 8; ++e) { oh[e] = hbuf[e]; oc[e] = cbuf[e]; }
}

// ---------------- launch ----------------
extern "C" void kernel_launch(void* const* d_in, const int* in_sizes, int n_in,
                              void* d_out, int out_size, void* d_ws, size_t ws_size,
                              hipStream_t stream) {
  const float* x      = (const float*)d_in[0];
  const float* h_prev = (const float*)d_in[1];
  const float* c_prev = (const float*)d_in[2];
  const float* Wi_w = (const float*)d_in[3];  const float* Wi_b = (const float*)d_in[4];
  const float* Wf_w = (const float*)d_in[5];  const float* Wf_b = (const float*)d_in[6];
  const float* Wo_w = (const float*)d_in[7];  const float* Wo_b = (const float*)d_in[8];
  const float* Wc_w = (const float*)d_in[9];  const float* Wc_b = (const float*)d_in[10];
  const float* Ws_w = (const float*)d_in[11]; const float* Ws_b = (const float*)d_in[12];
  const float* Ui_w = (const float*)d_in[13]; const float* Ui_b = (const float*)d_in[14];
  const float* Uf_w = (const float*)d_in[15]; const float* Uf_b = (const float*)d_in[16];
  const float* Uo_w = (const float*)d_in[17]; const float* Uo_b = (const float*)d_in[18];
  const float* Uc_w = (const float*)d_in[19]; const float* Uc_b = (const float*)d_in[20];
  const float* Us_w = (const float*)d_in[21]; const float* Us_b = (const float*)d_in[22];
  const float* a1_w = (const float*)d_in[23]; const float* a1_b = (const float*)d_in[24];
  const float* a2_w = (const float*)d_in[25]; const float* a2_b = (const float*)d_in[26];
  const float* r1_w = (const float*)d_in[27]; const float* r1_b = (const float*)d_in[28];
  const float* r2_w = (const float*)d_in[29]; const float* r2_b = (const float*)d_in[30];
  const float* r3_w = (const float*)d_in[31]; const float* r3_b = (const float*)d_in[32];

  char* ws = (char*)d_ws;
  size_t off = 0;
  auto alloc = [&](size_t bytes) -> void* {
    void* p = ws + off;
    off += (bytes + 255) & ~(size_t)255;
    return p;
  };
  bf16* A_big    = (bf16*)alloc((size_t)8192 * 2048 * 2);
  bf16* WG       = (bf16*)alloc((size_t)7168 * 2048 * 2);
  float* bias_bg = (float*)alloc((size_t)7168 * 4);
  bf16* WR2      = (bf16*)alloc((size_t)1024 * 1024 * 2);
  bf16* WR3      = (bf16*)alloc((size_t)1024 * 1024 * 2);
  bf16* G        = (bf16*)alloc((size_t)8192 * 7168 * 2);
  bf16* R2       = (bf16*)alloc((size_t)8192 * 1024 * 2);
  bf16* R3       = (bf16*)alloc((size_t)8192 * 1024 * 2);
  float* alpha   = (float*)alloc((size_t)8192 * 4);

  build_A<<<16384, 256, 0, stream>>>(x, h_prev, A_big);
  build_WG<<<14336, 256, 0, stream>>>(Wi_w, Wf_w, Wo_w, Wc_w, Ws_w,
                                      Ui_w, Uf_w, Uo_w, Uc_w, Us_w, a1_w, r1_w, WG);
  build_bias<<<28, 256, 0, stream>>>(Wi_b, Wf_b, Wo_b, Wc_b, Ws_b,
                                     Ui_b, Uf_b, Uo_b, Uc_b, Us_b, a1_b, r1_b, bias_bg);
  f2b<<<1024, 256, 0, stream>>>(r2_w, WR2, 262144);
  f2b<<<1024, 256, 0, stream>>>(r3_w, WR3, 262144);

  // big fused GEMM: [8192 x 2048] @ [7168 x 2048]^T, 256^2 deep-pipelined 8-phase
  gemm256<<<32 * 28, 512, 0, stream>>>(A_big, 2048, WG, 2048, 2048, bias_bg, G, NBIG, 0, 32);

  // alpha head
  alpha_k<<<2048, 256, 0, stream>>>(G, a2_w, a2_b, alpha);

  // residual chain r2 -> r3 (128^2 kernel)
  dim3 g2(64, 8);
  gemm_bt<<<g2, 256, 0, stream>>>(G + 6144, NBIG, WR2, 1024, r2_b, R2, 1024, 1);
  gemm_bt<<<g2, 256, 0, stream>>>(R2, 1024, WR3, 1024, r3_b, R3, 1024, 2);

  final_k<<<4096, 256, 0, stream>>>(G, R3, c_prev, alpha, (float*)d_out);
}